// Round 1
// baseline (441.412 us; speedup 1.0000x reference)
//
#include <hip/hip_runtime.h>
#include <hip/hip_bf16.h>

#define NB 16
#define TT 2048
#define CC 384

typedef short bf16x8 __attribute__((ext_vector_type(8)));
typedef float f32x4 __attribute__((ext_vector_type(4)));

static __device__ __forceinline__ short f2bf(float f) {
  union { __hip_bfloat16 h; short s; } u;
  u.h = __float2bfloat16(f);
  return u.s;
}

// C^-0.5 * log2(e): folded into Q at projection time (attn works in exp2 domain)
#define QSC (0.051031036307982884f * 1.4426950408889634f)

// ---------------------------------------------------------------------------
// W[3] (fp32 [C][H]) -> Wbt (bf16 [3][n=H][k=C])  (transposed for LDS staging)
// ---------------------------------------------------------------------------
__global__ __launch_bounds__(384)
void conv_wt(const float* __restrict__ Wq, const float* __restrict__ Wk,
             const float* __restrict__ Wv, short* __restrict__ Wbt) {
  const int w = blockIdx.x / CC;
  const int n = blockIdx.x % CC;
  const int k = threadIdx.x;
  const float* W = (w == 0) ? Wq : (w == 1) ? Wk : Wv;
  Wbt[((size_t)w * CC + n) * CC + k] = f2bf(W[(size_t)k * CC + n]);
}

// ---------------------------------------------------------------------------
// Fused QKV projection GEMM: [32768 x 384](fp32 x, converted in-reg) x
// [384 x 1152] bf16 MFMA, register-prefetch pipelined.
// n-tiles 0-2 -> Q (pre-scaled by QSC), 3-5 -> K, 6-8 -> V transposed to
// Vt[b][d][t] via LDS transpose epilogue.
// ---------------------------------------------------------------------------
__global__ __launch_bounds__(256, 3)
void proj_gemm(const float* __restrict__ x, const short* __restrict__ Wbt,
               short* __restrict__ Q, short* __restrict__ K,
               short* __restrict__ Vt) {
  __shared__ char smem[34816];           // staging (2x10240) U epilogue (34816)
  short* As = (short*)smem;              // [128][40] shorts (32 data + 8 pad)
  short* Bs = (short*)(smem + 10240);    // [128][40]
  short* Es = (short*)smem;              // epilogue [128][136]

  const int mt = blockIdx.x & 255;
  const int nt = blockIdx.x >> 8;        // 0..8
  const int wsel = nt / 3;               // 0=Q,1=K,2=V
  const int nc0 = (nt % 3) * 128;
  const int tid = threadIdx.x;
  const int wave = tid >> 6, lane = tid & 63;
  const int l15 = lane & 15, quad = lane >> 4;
  const int wm = (wave & 1) * 64, wn = (wave >> 1) * 64;

  const float* Ab = x + (size_t)mt * 128 * CC;
  const short* Bb = Wbt + ((size_t)wsel * CC + nc0) * CC;

  f32x4 acc[16];
  #pragma unroll
  for (int i = 0; i < 16; ++i) acc[i] = f32x4{0.f, 0.f, 0.f, 0.f};

  // prefetch registers
  float4 ra[4];
  bf16x8 rb[2];
  #pragma unroll
  for (int c = 0; c < 4; ++c) {
    const int ci = c * 256 + tid;        // float4-chunk, 0..1023
    ra[c] = *(const float4*)(Ab + (size_t)(ci >> 3) * CC + (ci & 7) * 4);
  }
  #pragma unroll
  for (int c = 0; c < 2; ++c) {
    const int ci = c * 256 + tid;        // 16B-chunk, 0..511
    rb[c] = *(const bf16x8*)(Bb + (size_t)(ci >> 2) * CC + (ci & 3) * 8);
  }

  for (int kt = 0; kt < 12; ++kt) {
    __syncthreads();
    #pragma unroll
    for (int c = 0; c < 4; ++c) {
      const int ci = c * 256 + tid;
      short4 s4;
      s4.x = f2bf(ra[c].x); s4.y = f2bf(ra[c].y);
      s4.z = f2bf(ra[c].z); s4.w = f2bf(ra[c].w);
      *(short4*)((char*)As + (ci >> 3) * 80 + (ci & 7) * 8) = s4;
    }
    #pragma unroll
    for (int c = 0; c < 2; ++c) {
      const int ci = c * 256 + tid;
      *(bf16x8*)((char*)Bs + (ci >> 2) * 80 + (ci & 3) * 16) = rb[c];
    }
    __syncthreads();
    if (kt < 11) {
      const int k0 = (kt + 1) * 32;
      #pragma unroll
      for (int c = 0; c < 4; ++c) {
        const int ci = c * 256 + tid;
        ra[c] = *(const float4*)(Ab + (size_t)(ci >> 3) * CC + k0 + (ci & 7) * 4);
      }
      #pragma unroll
      for (int c = 0; c < 2; ++c) {
        const int ci = c * 256 + tid;
        rb[c] = *(const bf16x8*)(Bb + (size_t)(ci >> 2) * CC + k0 + (ci & 3) * 8);
      }
    }
    bf16x8 af[4], bf[4];
    #pragma unroll
    for (int i = 0; i < 4; ++i) {
      af[i] = *(const bf16x8*)((char*)As + (wm + i * 16 + l15) * 80 + quad * 16);
      bf[i] = *(const bf16x8*)((char*)Bs + (wn + i * 16 + l15) * 80 + quad * 16);
    }
    #pragma unroll
    for (int i = 0; i < 4; ++i)
      #pragma unroll
      for (int j = 0; j < 4; ++j)
        acc[i * 4 + j] =
            __builtin_amdgcn_mfma_f32_16x16x32_bf16(af[i], bf[j], acc[i * 4 + j], 0, 0, 0);
  }

  if (nt < 6) {
    short* O = (nt < 3) ? Q : K;
    const float sc = (nt < 3) ? QSC : 1.0f;
    #pragma unroll
    for (int i = 0; i < 4; ++i)
      #pragma unroll
      for (int j = 0; j < 4; ++j) {
        const f32x4 a = acc[i * 4 + j];
        const int r0 = mt * 128 + wm + i * 16 + quad * 4;
        const int c = nc0 + wn + j * 16 + l15;
        #pragma unroll
        for (int r = 0; r < 4; ++r) O[(size_t)(r0 + r) * CC + c] = f2bf(a[r] * sc);
      }
  } else {
    __syncthreads();                     // done with As/Bs; reuse as Es
    #pragma unroll
    for (int i = 0; i < 4; ++i)
      #pragma unroll
      for (int j = 0; j < 4; ++j) {
        const f32x4 a = acc[i * 4 + j];
        const int dl = wn + j * 16 + l15;       // local col (d)
        const int ml = wm + i * 16 + quad * 4;  // local row (t)
        short4 p4;
        p4.x = f2bf(a[0]); p4.y = f2bf(a[1]); p4.z = f2bf(a[2]); p4.w = f2bf(a[3]);
        *(short4*)(Es + (size_t)dl * 136 + ml) = p4;
      }
    __syncthreads();
    const int d0 = (nt - 6) * 128;
    const int b = mt >> 4, t0 = (mt & 15) * 128;
    const int dr = tid >> 1, hf = tid & 1;
    const short* src = Es + (size_t)dr * 136 + hf * 64;
    short* dst = Vt + ((size_t)b * CC + d0 + dr) * TT + t0 + hf * 64;
    #pragma unroll
    for (int c = 0; c < 8; ++c)
      *(bf16x8*)(dst + c * 8) = *(const bf16x8*)(src + c * 8);
  }
}

// ---------------------------------------------------------------------------
// Flash attention, causal. Block = 64 queries / 4 waves, 32-key chunks,
// register-prefetch pipelined LDS staging, l-sum via ones-MFMA.
// NEW vs prev round:
//  * Complement-paired grid: blk<256 -> qt=31..16 (longest first),
//    blk>=256 -> qt=0..15 ascending. Pair (i, i+256) on one CU sums to a
//    constant 66 chunk-units (was 96..36 -> 45% makespan slack).
//    XCD locality preserved: b = blk&15 in both halves.
//  * XOR-swizzled unpadded LDS tiles (Ks 32x768B, Vs 384x64B):
//    old Ks row stride 784B ≡ 4 dwords (mod 32) put all 64 lanes on 8
//    bank-groups (8-way conflict, 1.6e7 conflict cycles). Swizzle gives
//    2 lanes/bank-group (free). LDS: 60928 -> 54272 B.
// ---------------------------------------------------------------------------
__global__ __launch_bounds__(256, 2)
void attn_kernel(const short* __restrict__ Q, const short* __restrict__ K,
                 const short* __restrict__ Vt, float* __restrict__ out) {
  __shared__ char sm[54272];
  char* Ks = sm;                            // [32 keys][48 slots^row 16B] 24576
  char* Vs = sm + 24576;                    // [384 d][4 slots+rot 16B]    24576
  short* Ps = (short*)(sm + 49152);         // [4 waves][16][40]           5120

  const int blk = blockIdx.x;
  const int qt = (blk < 256) ? (31 - (blk >> 4)) : ((blk >> 4) - 16);
  const int b  = blk & 15;                  // XCD = blk%8 = b%8
  const int q0b = qt * 64;
  const int tid = threadIdx.x;
  const int wave = tid >> 6, lane = tid & 63;
  const int l15 = lane & 15, quad = lane >> 4;
  const int q0 = q0b + wave * 16;
  short* pw = Ps + wave * 640;

  // Q fragments resident in registers (Q pre-scaled by QSC)
  bf16x8 qf[12];
  const short* qp = Q + ((size_t)b * TT + q0 + l15) * CC + quad * 8;
  #pragma unroll
  for (int ks = 0; ks < 12; ++ks) qf[ks] = *(const bf16x8*)(qp + ks * 32);

  f32x4 o[24];
  #pragma unroll
  for (int n = 0; n < 24; ++n) o[n] = f32x4{0.f, 0.f, 0.f, 0.f};
  f32x4 lsum = f32x4{0.f, 0.f, 0.f, 0.f};
  float m[4];
  #pragma unroll
  for (int r = 0; r < 4; ++r) m[r] = -INFINITY;

  bf16x8 onesf;
  #pragma unroll
  for (int i = 0; i < 8; ++i) onesf[i] = (short)0x3F80;   // bf16 1.0

  const short* kb  = K  + (size_t)b * TT * CC;
  const short* vtb = Vt + (size_t)b * CC * TT;
  const int nchunk = qt * 2 + 2;

  // prefetch chunk 0
  bf16x8 rk[6], rv[6];
  #pragma unroll
  for (int c = 0; c < 6; ++c) {
    const int ci = c * 256 + tid;
    rk[c] = *(const bf16x8*)(kb + (size_t)(ci / 48) * CC + (ci % 48) * 8);
    rv[c] = *(const bf16x8*)(vtb + (size_t)(ci >> 2) * TT + (ci & 3) * 8);
  }

  for (int kc = 0; kc < nchunk; ++kc) {
    const int k0 = kc * 32;
    __syncthreads();                       // all waves done reading prev chunk
    #pragma unroll
    for (int c = 0; c < 6; ++c) {
      const int ci = c * 256 + tid;
      const int kr = ci / 48, kslot = ci % 48;
      *(bf16x8*)(Ks + kr * 768 + ((kslot ^ (kr & 7)) << 4)) = rk[c];
      const int vr = ci >> 2, vslot = ci & 3;
      *(bf16x8*)(Vs + vr * 64 + (((vslot + (vr >> 2)) & 3) << 4)) = rv[c];
    }
    __syncthreads();
    if (kc + 1 < nchunk) {                 // issue next chunk's loads now
      const int kn = k0 + 32;
      #pragma unroll
      for (int c = 0; c < 6; ++c) {
        const int ci = c * 256 + tid;
        rk[c] = *(const bf16x8*)(kb + (size_t)(kn + ci / 48) * CC + (ci % 48) * 8);
        rv[c] = *(const bf16x8*)(vtb + (size_t)(ci >> 2) * TT + kn + (ci & 3) * 8);
      }
    }
    if (k0 > q0 + 15) continue;            // fully masked for this wave

    // ---- S = Q K^T (16 q x 32 keys), already in log2 domain via Q scaling
    f32x4 s0 = f32x4{0.f, 0.f, 0.f, 0.f};
    f32x4 s1 = f32x4{0.f, 0.f, 0.f, 0.f};
    #pragma unroll
    for (int ks = 0; ks < 12; ++ks) {
      const int sl = (ks * 4 + quad) ^ (l15 & 7);
      const bf16x8 b0 = *(const bf16x8*)(Ks + l15 * 768 + (sl << 4));
      const bf16x8 b1 = *(const bf16x8*)(Ks + (16 + l15) * 768 + (sl << 4));
      s0 = __builtin_amdgcn_mfma_f32_16x16x32_bf16(qf[ks], b0, s0, 0, 0, 0);
      s1 = __builtin_amdgcn_mfma_f32_16x16x32_bf16(qf[ks], b1, s1, 0, 0, 0);
    }
    // ---- causal mask + row max (shuffles within 16-lane col groups)
    const bool domask = (k0 + 31 > q0);
    float mx[4];
    #pragma unroll
    for (int r = 0; r < 4; ++r) {
      float a = s0[r], c = s1[r];
      if (domask) {
        const int qg = q0 + quad * 4 + r;
        if (k0 + l15 > qg)      a = -INFINITY;
        if (k0 + 16 + l15 > qg) c = -INFINITY;
      }
      s0[r] = a; s1[r] = c;
      float v = fmaxf(a, c);
      v = fmaxf(v, __shfl_xor(v, 1));
      v = fmaxf(v, __shfl_xor(v, 2));
      v = fmaxf(v, __shfl_xor(v, 4));
      v = fmaxf(v, __shfl_xor(v, 8));
      mx[r] = v;
    }
    // ---- online softmax update (exp2 domain); row-sum comes from ones-MFMA
    float alpha[4];
    #pragma unroll
    for (int r = 0; r < 4; ++r) {
      const float mn = fmaxf(m[r], mx[r]);
      alpha[r] = exp2f(m[r] - mn);
      m[r] = mn;
      s0[r] = exp2f(s0[r] - mn);
      s1[r] = exp2f(s1[r] - mn);
    }
    const bool need = (alpha[0] < 1.f) | (alpha[1] < 1.f) |
                      (alpha[2] < 1.f) | (alpha[3] < 1.f);
    if (__any(need)) {
      #pragma unroll
      for (int r = 0; r < 4; ++r) lsum[r] *= alpha[r];
      #pragma unroll
      for (int n = 0; n < 24; ++n) {
        #pragma unroll
        for (int r = 0; r < 4; ++r) o[n][r] *= alpha[r];
      }
    }
    // ---- P: C-layout -> A-layout via wave-private LDS
    #pragma unroll
    for (int r = 0; r < 4; ++r) {
      pw[(quad * 4 + r) * 40 + l15]      = f2bf(s0[r]);
      pw[(quad * 4 + r) * 40 + 16 + l15] = f2bf(s1[r]);
    }
    const bf16x8 pf = *(const bf16x8*)(pw + l15 * 40 + quad * 8);
    // ---- l += P . 1 (one MFMA replaces the shuffle-sum chain)
    lsum = __builtin_amdgcn_mfma_f32_16x16x32_bf16(pf, onesf, lsum, 0, 0, 0);
    // ---- O += P V
    #pragma unroll
    for (int n = 0; n < 24; ++n) {
      const int vrow = n * 16 + l15;
      const bf16x8 vf = *(const bf16x8*)(Vs + vrow * 64 + (((quad + (vrow >> 2)) & 3) << 4));
      o[n] = __builtin_amdgcn_mfma_f32_16x16x32_bf16(pf, vf, o[n], 0, 0, 0);
    }
  }

  // ---- epilogue
  float linv[4];
  #pragma unroll
  for (int r = 0; r < 4; ++r) linv[r] = 1.f / lsum[r];
  float* ob = out + ((size_t)b * TT + q0) * CC;
  #pragma unroll
  for (int n = 0; n < 24; ++n) {
    #pragma unroll
    for (int r = 0; r < 4; ++r) {
      ob[(size_t)(quad * 4 + r) * CC + n * 16 + l15] = o[n][r] * linv[r];
    }
  }
}

extern "C" void kernel_launch(void* const* d_in, const int* in_sizes, int n_in,
                              void* d_out, int out_size, void* d_ws, size_t ws_size,
                              hipStream_t stream) {
  const float* x  = (const float*)d_in[0];
  const float* Wq = (const float*)d_in[1];
  const float* Wk = (const float*)d_in[2];
  const float* Wv = (const float*)d_in[3];
  float* out = (float*)d_out;

  const size_t QS = (size_t)NB * TT * CC;     // 12.58M elems
  short* Qs = (short*)d_ws;
  short* Ks = Qs + QS;
  short* Vt = Ks + QS;                        // ws: 75.5 MB

  // bf16 W^T staging lives in d_out (50 MB fp32) until attn overwrites it
  short* Wbt = (short*)d_out;                 // 0.9 MB

  hipLaunchKernelGGL(conv_wt, dim3(3 * CC), dim3(CC), 0, stream, Wq, Wk, Wv, Wbt);
  hipLaunchKernelGGL(proj_gemm, dim3(256 * 9), dim3(256), 0, stream,
                     x, Wbt, Qs, Ks, Vt);
  hipLaunchKernelGGL(attn_kernel, dim3(NB * TT / 64), dim3(256), 0, stream,
                     Qs, Ks, Vt, out);
}

// Round 2
// 312.063 us; speedup vs baseline: 1.4145x; 1.4145x over previous
//
#include <hip/hip_runtime.h>
#include <hip/hip_bf16.h>

#define NB 16
#define TT 2048
#define CC 384

typedef short bf16x8 __attribute__((ext_vector_type(8)));
typedef float f32x4 __attribute__((ext_vector_type(4)));

static __device__ __forceinline__ short f2bf(float f) {
  union { __hip_bfloat16 h; short s; } u;
  u.h = __float2bfloat16(f);
  return u.s;
}

// C^-0.5 * log2(e): folded into Q at projection time (attn works in exp2 domain)
#define QSC (0.051031036307982884f * 1.4426950408889634f)

// ---------------------------------------------------------------------------
// W[3] (fp32 [C][H]) -> Wbt (bf16 [3][n=H][k=C])  (transposed for LDS staging)
// ---------------------------------------------------------------------------
__global__ __launch_bounds__(384)
void conv_wt(const float* __restrict__ Wq, const float* __restrict__ Wk,
             const float* __restrict__ Wv, short* __restrict__ Wbt) {
  const int w = blockIdx.x / CC;
  const int n = blockIdx.x % CC;
  const int k = threadIdx.x;
  const float* W = (w == 0) ? Wq : (w == 1) ? Wk : Wv;
  Wbt[((size_t)w * CC + n) * CC + k] = f2bf(W[(size_t)k * CC + n]);
}

// ---------------------------------------------------------------------------
// Fused QKV projection GEMM: [32768 x 384](fp32 x, converted in-reg) x
// [384 x 1152] bf16 MFMA, register-prefetch pipelined.
// n-tiles 0-2 -> Q (pre-scaled by QSC), 3-5 -> K, 6-8 -> V transposed to
// Vt[b][d][t] via LDS transpose epilogue.
// ---------------------------------------------------------------------------
__global__ __launch_bounds__(256, 3)
void proj_gemm(const float* __restrict__ x, const short* __restrict__ Wbt,
               short* __restrict__ Q, short* __restrict__ K,
               short* __restrict__ Vt) {
  __shared__ char smem[34816];           // staging (2x10240) U epilogue (34816)
  short* As = (short*)smem;              // [128][40] shorts (32 data + 8 pad)
  short* Bs = (short*)(smem + 10240);    // [128][40]
  short* Es = (short*)smem;              // epilogue [128][136]

  const int mt = blockIdx.x & 255;
  const int nt = blockIdx.x >> 8;        // 0..8
  const int wsel = nt / 3;               // 0=Q,1=K,2=V
  const int nc0 = (nt % 3) * 128;
  const int tid = threadIdx.x;
  const int wave = tid >> 6, lane = tid & 63;
  const int l15 = lane & 15, quad = lane >> 4;
  const int wm = (wave & 1) * 64, wn = (wave >> 1) * 64;

  const float* Ab = x + (size_t)mt * 128 * CC;
  const short* Bb = Wbt + ((size_t)wsel * CC + nc0) * CC;

  f32x4 acc[16];
  #pragma unroll
  for (int i = 0; i < 16; ++i) acc[i] = f32x4{0.f, 0.f, 0.f, 0.f};

  // prefetch registers
  float4 ra[4];
  bf16x8 rb[2];
  #pragma unroll
  for (int c = 0; c < 4; ++c) {
    const int ci = c * 256 + tid;        // float4-chunk, 0..1023
    ra[c] = *(const float4*)(Ab + (size_t)(ci >> 3) * CC + (ci & 7) * 4);
  }
  #pragma unroll
  for (int c = 0; c < 2; ++c) {
    const int ci = c * 256 + tid;        // 16B-chunk, 0..511
    rb[c] = *(const bf16x8*)(Bb + (size_t)(ci >> 2) * CC + (ci & 3) * 8);
  }

  for (int kt = 0; kt < 12; ++kt) {
    __syncthreads();
    #pragma unroll
    for (int c = 0; c < 4; ++c) {
      const int ci = c * 256 + tid;
      short4 s4;
      s4.x = f2bf(ra[c].x); s4.y = f2bf(ra[c].y);
      s4.z = f2bf(ra[c].z); s4.w = f2bf(ra[c].w);
      *(short4*)((char*)As + (ci >> 3) * 80 + (ci & 7) * 8) = s4;
    }
    #pragma unroll
    for (int c = 0; c < 2; ++c) {
      const int ci = c * 256 + tid;
      *(bf16x8*)((char*)Bs + (ci >> 2) * 80 + (ci & 3) * 16) = rb[c];
    }
    __syncthreads();
    if (kt < 11) {
      const int k0 = (kt + 1) * 32;
      #pragma unroll
      for (int c = 0; c < 4; ++c) {
        const int ci = c * 256 + tid;
        ra[c] = *(const float4*)(Ab + (size_t)(ci >> 3) * CC + k0 + (ci & 7) * 4);
      }
      #pragma unroll
      for (int c = 0; c < 2; ++c) {
        const int ci = c * 256 + tid;
        rb[c] = *(const bf16x8*)(Bb + (size_t)(ci >> 2) * CC + k0 + (ci & 3) * 8);
      }
    }
    bf16x8 af[4], bf[4];
    #pragma unroll
    for (int i = 0; i < 4; ++i) {
      af[i] = *(const bf16x8*)((char*)As + (wm + i * 16 + l15) * 80 + quad * 16);
      bf[i] = *(const bf16x8*)((char*)Bs + (wn + i * 16 + l15) * 80 + quad * 16);
    }
    #pragma unroll
    for (int i = 0; i < 4; ++i)
      #pragma unroll
      for (int j = 0; j < 4; ++j)
        acc[i * 4 + j] =
            __builtin_amdgcn_mfma_f32_16x16x32_bf16(af[i], bf[j], acc[i * 4 + j], 0, 0, 0);
  }

  if (nt < 6) {
    short* O = (nt < 3) ? Q : K;
    const float sc = (nt < 3) ? QSC : 1.0f;
    #pragma unroll
    for (int i = 0; i < 4; ++i)
      #pragma unroll
      for (int j = 0; j < 4; ++j) {
        const f32x4 a = acc[i * 4 + j];
        const int r0 = mt * 128 + wm + i * 16 + quad * 4;
        const int c = nc0 + wn + j * 16 + l15;
        #pragma unroll
        for (int r = 0; r < 4; ++r) O[(size_t)(r0 + r) * CC + c] = f2bf(a[r] * sc);
      }
  } else {
    __syncthreads();                     // done with As/Bs; reuse as Es
    #pragma unroll
    for (int i = 0; i < 4; ++i)
      #pragma unroll
      for (int j = 0; j < 4; ++j) {
        const f32x4 a = acc[i * 4 + j];
        const int dl = wn + j * 16 + l15;       // local col (d)
        const int ml = wm + i * 16 + quad * 4;  // local row (t)
        short4 p4;
        p4.x = f2bf(a[0]); p4.y = f2bf(a[1]); p4.z = f2bf(a[2]); p4.w = f2bf(a[3]);
        *(short4*)(Es + (size_t)dl * 136 + ml) = p4;
      }
    __syncthreads();
    const int d0 = (nt - 6) * 128;
    const int b = mt >> 4, t0 = (mt & 15) * 128;
    const int dr = tid >> 1, hf = tid & 1;
    const short* src = Es + (size_t)dr * 136 + hf * 64;
    short* dst = Vt + ((size_t)b * CC + d0 + dr) * TT + t0 + hf * 64;
    #pragma unroll
    for (int c = 0; c < 8; ++c)
      *(bf16x8*)(dst + c * 8) = *(const bf16x8*)(src + c * 8);
  }
}

// ---------------------------------------------------------------------------
// Flash attention, causal. Block = 64 queries / 4 waves, 32-key chunks.
// NEW vs prev round:
//  * Grid order reverted to round-0 (qt = 31 - blk>>4, proven 280us; the
//    complement pairing regressed because co-resident blocks run
//    concurrently: the short partner exits and the long block runs solo).
//  * Staging via __builtin_amdgcn_global_load_lds (16B, async, no VGPR
//    round-trip) with raw s_barrier + counted s_waitcnt vmcnt(6):
//    K(kc+1) issued after the QK^T read-barrier (lands during softmax+PV),
//    V(kc+1) issued after the PV read-barrier (lands during next QK^T).
//    vmcnt never drains to 0 inside the loop -> global latency fully hidden,
//    ~36 fewer live VGPRs, no ds_write phase.
//  * LDS layouts unchanged (K XOR-swizzle / V rotate) achieved by
//    pre-swizzling the per-lane GLOBAL source address; LDS dest is linear
//    (wave-uniform base + lane*16) as global_load_lds requires.
// ---------------------------------------------------------------------------
__global__ __launch_bounds__(256, 2)
void attn_kernel(const short* __restrict__ Q, const short* __restrict__ K,
                 const short* __restrict__ Vt, float* __restrict__ out) {
  __shared__ char sm[54272];
  char* Ks = sm;                            // [32 keys][48 slots^row 16B] 24576
  char* Vs = sm + 24576;                    // [384 d][4 slots+rot 16B]    24576
  short* Ps = (short*)(sm + 49152);         // [4 waves][16][40]           5120

  const int blk = blockIdx.x;
  const int qt = 31 - (blk >> 4);           // descending work order
  const int b  = blk & 15;                  // XCD = blk%8 = b%8
  const int q0b = qt * 64;
  const int tid = threadIdx.x;
  const int wave = tid >> 6, lane = tid & 63;
  const int l15 = lane & 15, quad = lane >> 4;
  const int q0 = q0b + wave * 16;
  short* pw = Ps + wave * 640;

  // Q fragments resident in registers (Q pre-scaled by QSC)
  bf16x8 qf[12];
  const short* qp = Q + ((size_t)b * TT + q0 + l15) * CC + quad * 8;
  #pragma unroll
  for (int ks = 0; ks < 12; ++ks) qf[ks] = *(const bf16x8*)(qp + ks * 32);

  f32x4 o[24];
  #pragma unroll
  for (int n = 0; n < 24; ++n) o[n] = f32x4{0.f, 0.f, 0.f, 0.f};
  f32x4 lsum = f32x4{0.f, 0.f, 0.f, 0.f};
  float m[4];
  #pragma unroll
  for (int r = 0; r < 4; ++r) m[r] = -INFINITY;

  bf16x8 onesf;
  #pragma unroll
  for (int i = 0; i < 8; ++i) onesf[i] = (short)0x3F80;   // bf16 1.0

  // per-lane pre-swizzled global source offsets for the 6 K and 6 V issues
  // (each wave stages 6 KB of K and 6 KB of V per chunk, 1 KB per issue)
  int koff[6], voff[6];
  #pragma unroll
  for (int j = 0; j < 6; ++j) {
    const int lin = wave * 6144 + j * 1024 + lane * 16;  // linear LDS byte
    const int kr = lin / 768;                            // K row (768 B rows)
    const int ksl = (lin - kr * 768) >> 4;               // K 16B slot
    koff[j] = kr * 768 + ((ksl ^ (kr & 7)) << 4);        // inverse XOR swizzle
    const int vr = lin >> 6;                             // V row (64 B rows)
    const int vsl = (lin >> 4) & 3;
    voff[j] = vr * 4096 + (((vsl - (vr >> 2)) & 3) << 4);  // inverse rotate
  }
  const char* kbB = (const char*)(K + (size_t)b * TT * CC);
  const char* vtB = (const char*)(Vt + (size_t)b * CC * TT);
  char* KsW = Ks + wave * 6144;
  char* VsW = Vs + wave * 6144;

  const int nchunk = qt * 2 + 2;

  // prologue: stage chunk 0 (K then V -> per-wave vmem queue [K:6, V:6])
  #pragma unroll
  for (int j = 0; j < 6; ++j)
    __builtin_amdgcn_global_load_lds(
        (const __attribute__((address_space(1))) void*)(kbB + koff[j]),
        (__attribute__((address_space(3))) void*)(KsW + j * 1024), 16, 0, 0);
  #pragma unroll
  for (int j = 0; j < 6; ++j)
    __builtin_amdgcn_global_load_lds(
        (const __attribute__((address_space(1))) void*)(vtB + voff[j]),
        (__attribute__((address_space(3))) void*)(VsW + j * 1024), 16, 0, 0);

  for (int kc = 0; kc < nchunk; ++kc) {
    const int k0 = kc * 32;
    const bool active = (k0 <= q0 + 15);
    // next chunk's key base (clamped dummy re-load on the last iteration)
    const int kn = (k0 + 32 < TT - 32) ? (k0 + 32) : (TT - 32);

    // ---- K(kc) ready (oldest 6 of [K:6, V:6]); barrier makes it visible
    asm volatile("s_waitcnt vmcnt(6)" ::: "memory");
    __builtin_amdgcn_s_barrier();
    __builtin_amdgcn_sched_barrier(0);

    f32x4 s0 = f32x4{0.f, 0.f, 0.f, 0.f};
    f32x4 s1 = f32x4{0.f, 0.f, 0.f, 0.f};
    if (active) {
      // ---- S = Q K^T (16 q x 32 keys), already in log2 domain
      #pragma unroll
      for (int ks = 0; ks < 12; ++ks) {
        const int sl = (ks * 4 + quad) ^ (l15 & 7);
        const bf16x8 b0 = *(const bf16x8*)(Ks + l15 * 768 + (sl << 4));
        const bf16x8 b1 = *(const bf16x8*)(Ks + (16 + l15) * 768 + (sl << 4));
        s0 = __builtin_amdgcn_mfma_f32_16x16x32_bf16(qf[ks], b0, s0, 0, 0, 0);
        s1 = __builtin_amdgcn_mfma_f32_16x16x32_bf16(qf[ks], b1, s1, 0, 0, 0);
      }
    }
    __builtin_amdgcn_sched_barrier(0);
    __builtin_amdgcn_s_barrier();          // all waves done reading Ks

    // ---- issue K(kc+1) (lands during softmax+PV)
    #pragma unroll
    for (int j = 0; j < 6; ++j)
      __builtin_amdgcn_global_load_lds(
          (const __attribute__((address_space(1))) void*)(kbB + (size_t)kn * 768 + koff[j]),
          (__attribute__((address_space(3))) void*)(KsW + j * 1024), 16, 0, 0);

    // ---- V(kc) ready (oldest 6 of [V:6, K':6])
    asm volatile("s_waitcnt vmcnt(6)" ::: "memory");
    __builtin_amdgcn_s_barrier();
    __builtin_amdgcn_sched_barrier(0);

    if (active) {
      // ---- causal mask + row max (shuffles within 16-lane col groups)
      const bool domask = (k0 + 31 > q0);
      float mx[4];
      #pragma unroll
      for (int r = 0; r < 4; ++r) {
        float a = s0[r], c = s1[r];
        if (domask) {
          const int qg = q0 + quad * 4 + r;
          if (k0 + l15 > qg)      a = -INFINITY;
          if (k0 + 16 + l15 > qg) c = -INFINITY;
        }
        s0[r] = a; s1[r] = c;
        float v = fmaxf(a, c);
        v = fmaxf(v, __shfl_xor(v, 1));
        v = fmaxf(v, __shfl_xor(v, 2));
        v = fmaxf(v, __shfl_xor(v, 4));
        v = fmaxf(v, __shfl_xor(v, 8));
        mx[r] = v;
      }
      // ---- online softmax update (exp2 domain)
      float alpha[4];
      #pragma unroll
      for (int r = 0; r < 4; ++r) {
        const float mn = fmaxf(m[r], mx[r]);
        alpha[r] = exp2f(m[r] - mn);
        m[r] = mn;
        s0[r] = exp2f(s0[r] - mn);
        s1[r] = exp2f(s1[r] - mn);
      }
      const bool need = (alpha[0] < 1.f) | (alpha[1] < 1.f) |
                        (alpha[2] < 1.f) | (alpha[3] < 1.f);
      if (__any(need)) {
        #pragma unroll
        for (int r = 0; r < 4; ++r) lsum[r] *= alpha[r];
        #pragma unroll
        for (int n = 0; n < 24; ++n) {
          #pragma unroll
          for (int r = 0; r < 4; ++r) o[n][r] *= alpha[r];
        }
      }
      // ---- P: C-layout -> A-layout via wave-private LDS
      #pragma unroll
      for (int r = 0; r < 4; ++r) {
        pw[(quad * 4 + r) * 40 + l15]      = f2bf(s0[r]);
        pw[(quad * 4 + r) * 40 + 16 + l15] = f2bf(s1[r]);
      }
      const bf16x8 pf = *(const bf16x8*)(pw + l15 * 40 + quad * 8);
      // ---- l += P . 1
      lsum = __builtin_amdgcn_mfma_f32_16x16x32_bf16(pf, onesf, lsum, 0, 0, 0);
      // ---- O += P V
      #pragma unroll
      for (int n = 0; n < 24; ++n) {
        const int vrow = n * 16 + l15;
        const bf16x8 vf = *(const bf16x8*)(Vs + vrow * 64 + (((quad + (vrow >> 2)) & 3) << 4));
        o[n] = __builtin_amdgcn_mfma_f32_16x16x32_bf16(pf, vf, o[n], 0, 0, 0);
      }
    }
    __builtin_amdgcn_sched_barrier(0);
    __builtin_amdgcn_s_barrier();          // all waves done reading Vs
    // ---- issue V(kc+1) (lands during next chunk's QK^T)
    #pragma unroll
    for (int j = 0; j < 6; ++j)
      __builtin_amdgcn_global_load_lds(
          (const __attribute__((address_space(1))) void*)(vtB + (size_t)kn * 2 + voff[j]),
          (__attribute__((address_space(3))) void*)(VsW + j * 1024), 16, 0, 0);
  }

  // ---- epilogue
  float linv[4];
  #pragma unroll
  for (int r = 0; r < 4; ++r) linv[r] = 1.f / lsum[r];
  float* ob = out + ((size_t)b * TT + q0) * CC;
  #pragma unroll
  for (int n = 0; n < 24; ++n) {
    #pragma unroll
    for (int r = 0; r < 4; ++r) {
      ob[(size_t)(quad * 4 + r) * CC + n * 16 + l15] = o[n][r] * linv[r];
    }
  }
}

extern "C" void kernel_launch(void* const* d_in, const int* in_sizes, int n_in,
                              void* d_out, int out_size, void* d_ws, size_t ws_size,
                              hipStream_t stream) {
  const float* x  = (const float*)d_in[0];
  const float* Wq = (const float*)d_in[1];
  const float* Wk = (const float*)d_in[2];
  const float* Wv = (const float*)d_in[3];
  float* out = (float*)d_out;

  const size_t QS = (size_t)NB * TT * CC;     // 12.58M elems
  short* Qs = (short*)d_ws;
  short* Ks = Qs + QS;
  short* Vt = Ks + QS;                        // ws: 75.5 MB

  // bf16 W^T staging lives in d_out (50 MB fp32) until attn overwrites it
  short* Wbt = (short*)d_out;                 // 0.9 MB

  hipLaunchKernelGGL(conv_wt, dim3(3 * CC), dim3(CC), 0, stream, Wq, Wk, Wv, Wbt);
  hipLaunchKernelGGL(proj_gemm, dim3(256 * 9), dim3(256), 0, stream,
                     x, Wbt, Qs, Ks, Vt);
  hipLaunchKernelGGL(attn_kernel, dim3(NB * TT / 64), dim3(256), 0, stream,
                     Qs, Ks, Vt, out);
}